// Round 7
// baseline (332.760 us; speedup 1.0000x reference)
//
#include <hip/hip_runtime.h>
#include <hip/hip_bf16.h>

#define H_DIM 2048
#define T_TOK 2048
#define E_NUM 16
#define I_DIM 1024
#define TOPK  4
#define NK1   32   // H_DIM/64
#define NK2   16   // I_DIM/64
#define MBMAX 80   // max Sum ceil(cnt_e/128) = 64 + 16

typedef short short8v __attribute__((ext_vector_type(8)));
typedef float f32x4v __attribute__((ext_vector_type(4)));
typedef unsigned short u16;
typedef unsigned int u32;

// ---------- ws layout (bytes) ----------
constexpr size_t OFF_XB   = 0;                                     // 8 MiB
constexpr size_t OFF_ABUF = OFF_XB   + (size_t)T_TOK*H_DIM*2;      // 16 MiB
constexpr size_t OFF_PBUF = OFF_ABUF + (size_t)T_TOK*TOPK*I_DIM*2; // 64 MiB
constexpr size_t OFF_SEL  = OFF_PBUF + (size_t)T_TOK*TOPK*H_DIM*4;
constexpr size_t OFF_WTS  = OFF_SEL  + (size_t)T_TOK*TOPK*4;
constexpr size_t OFF_CNT  = OFF_WTS  + (size_t)T_TOK*TOPK*4;
constexpr size_t OFF_OFFS = OFF_CNT  + 128;
constexpr size_t OFF_CURS = OFF_OFFS + 128;
constexpr size_t OFF_RTOK = OFF_CURS + 128;
constexpr size_t OFF_RWT  = OFF_RTOK + (size_t)T_TOK*TOPK*4;
constexpr size_t OFF_PPOS = OFF_RWT  + (size_t)T_TOK*TOPK*4;
constexpr size_t OFF_MBE  = OFF_PPOS + (size_t)T_TOK*TOPK*4;
constexpr size_t OFF_MBM0 = OFF_MBE  + 384;
constexpr size_t OFF_MBN  = OFF_MBM0 + 384;
constexpr size_t WS_NEED  = OFF_MBN  + 128;

// ---------- helpers ----------
__device__ __forceinline__ u16 f2b(float f) {   // fp32 -> bf16 RNE
  u32 u = __builtin_bit_cast(u32, f);
  u32 r = (u + 0x7FFFu + ((u >> 16) & 1u)) >> 16;
  return (u16)r;
}

__device__ __forceinline__ u32 cvtpk(float lo, float hi) {
  u32 r;
  asm("v_cvt_pk_bf16_f32 %0, %1, %2" : "=v"(r) : "v"(lo), "v"(hi));
  return r;
}

__device__ __forceinline__ void gld16(const void* g, void* l) {
  __builtin_amdgcn_global_load_lds(
      (const __attribute__((address_space(1))) u32*)g,
      (__attribute__((address_space(3))) u32*)l, 16, 0, 0);
}

#define SB0 __builtin_amdgcn_sched_barrier(0)
// steady-state: A(k+2)x4 + B(k+2)x8 = 12 outstanding survive the barrier
#define WAITBAR12 { SB0; asm volatile("s_waitcnt vmcnt(12) lgkmcnt(0)" ::: "memory"); \
                    __builtin_amdgcn_s_barrier(); SB0; }
#define WAITBAR0  { SB0; asm volatile("s_waitcnt vmcnt(0) lgkmcnt(0)" ::: "memory"); \
                    __builtin_amdgcn_s_barrier(); SB0; }
#define ROT3(Ac, An, Af) { char* _t = Ac; Ac = An; An = Af; Af = _t; }

// ---------- fp32 -> bf16 (x) ----------
__global__ __launch_bounds__(256) void cvt_x_kernel(const float* __restrict__ src,
                                                    u16* __restrict__ dst) {
  int i = blockIdx.x * 256 + threadIdx.x;
  const float4* s = (const float4*)src + (size_t)i * 2;
  float4 a = s[0], b = s[1];
  uint4 o;
  o.x = (u32)f2b(a.x) | ((u32)f2b(a.y) << 16);
  o.y = (u32)f2b(a.z) | ((u32)f2b(a.w) << 16);
  o.z = (u32)f2b(b.x) | ((u32)f2b(b.y) << 16);
  o.w = (u32)f2b(b.z) | ((u32)f2b(b.w) << 16);
  ((uint4*)dst)[i] = o;
}

// ---------- router ----------
__global__ __launch_bounds__(256) void router_kernel(const float* __restrict__ x,
                                                     const float* __restrict__ rw,
                                                     float* __restrict__ logits,
                                                     int* __restrict__ sel,
                                                     float* __restrict__ wts) {
  int w = threadIdx.x >> 6, lane = threadIdx.x & 63;
  int t = blockIdx.x * 4 + w;

  const float4* xt = (const float4*)(x + (size_t)t * H_DIM);
  float4 xv[8];
  #pragma unroll
  for (int j = 0; j < 8; ++j) xv[j] = xt[j * 64 + lane];

  const float4* rw4 = (const float4*)rw;
  float le[E_NUM];
  #pragma unroll
  for (int e = 0; e < E_NUM; ++e) {
    float s = 0.f;
    #pragma unroll
    for (int j = 0; j < 8; ++j) {
      float4 wv = rw4[e * (H_DIM / 4) + j * 64 + lane];
      s += xv[j].x * wv.x + xv[j].y * wv.y + xv[j].z * wv.z + xv[j].w * wv.w;
    }
    #pragma unroll
    for (int off = 32; off; off >>= 1) s += __shfl_xor(s, off);
    le[e] = s;
  }

  int taken = 0;
  float tv[TOPK]; int ti[TOPK];
  #pragma unroll
  for (int k = 0; k < TOPK; ++k) {
    float bv = -1e30f; int bi = 0;
    #pragma unroll
    for (int e = 0; e < E_NUM; ++e) {
      bool ok = !(taken & (1 << e));
      if (ok && le[e] > bv) { bv = le[e]; bi = e; }
    }
    taken |= (1 << bi); tv[k] = bv; ti[k] = bi;
  }
  float m = tv[0];
  float ew[TOPK]; float ssum = 0.f;
  #pragma unroll
  for (int k = 0; k < TOPK; ++k) { ew[k] = __expf(tv[k] - m); ssum += ew[k]; }
  if (lane == 0) {
    #pragma unroll
    for (int e = 0; e < E_NUM; ++e) logits[(size_t)t * E_NUM + e] = le[e];
    float inv = 1.f / ssum;
    #pragma unroll
    for (int k = 0; k < TOPK; ++k) {
      sel[t * TOPK + k] = ti[k];
      wts[t * TOPK + k] = ew[k] * inv;
    }
  }
}

// ---------- grouping ----------
__global__ void hist_kernel(const int* __restrict__ sel, int* __restrict__ cnt) {
  int p = blockIdx.x * 256 + threadIdx.x;
  if (p < T_TOK * TOPK) atomicAdd(&cnt[sel[p]], 1);
}

__global__ void prefix_kernel(const int* __restrict__ cnt, int* __restrict__ offs,
                              int* __restrict__ curs, int* __restrict__ mbe,
                              int* __restrict__ mbm0, int* __restrict__ mbn) {
  if (threadIdx.x == 0) {
    int a = 0;
    for (int e = 0; e < E_NUM; ++e) { offs[e] = a; curs[e] = a; a += cnt[e]; }
    offs[E_NUM] = a;
    // dense working-block map: mb -> (expert, m0)
    int nb = 0;
    for (int e = 0; e < E_NUM; ++e)
      for (int m0 = 0; m0 < cnt[e]; m0 += 128) {
        mbe[nb] = e; mbm0[nb] = m0; ++nb;
      }
    mbn[0] = nb;
  }
}

__global__ void scatter_kernel(const int* __restrict__ sel, const float* __restrict__ wts,
                               int* __restrict__ curs, int* __restrict__ rtok,
                               float* __restrict__ rwt, int* __restrict__ ppos) {
  int p = blockIdx.x * 256 + threadIdx.x;
  if (p >= T_TOK * TOPK) return;
  int e = sel[p];
  int pos = atomicAdd(&curs[e], 1);
  rtok[pos] = p >> 2;
  rwt[pos] = wts[p];
  ppos[p] = pos;
}

// ================= GEMM1: x @ [gate ; up] -> silu(g)*u*wt -> abuf (bf16) ==========
// 128M x 64N(out) tile, BK=64, dense mb-grid. Depth-2 pipeline (A 3-buf, B 2-deep regs).
__global__ __launch_bounds__(256, 2) void gemm1_kernel(
    const u16* __restrict__ xb, const float* __restrict__ wg, const float* __restrict__ wu,
    const int* __restrict__ cnt, const int* __restrict__ offs,
    const int* __restrict__ rtok, const float* __restrict__ rwt,
    const int* __restrict__ mbe, const int* __restrict__ mbm0,
    const int* __restrict__ mbn, u16* __restrict__ abuf) {
  int mb = blockIdx.y;
  if (mb >= mbn[0]) return;
  int e = mbe[mb];
  int m0 = mbm0[mb];
  int cntE = cnt[e];
  int n0 = blockIdx.x * 64;
  int base = offs[e];

  __shared__ alignas(16) char smem[81920];   // A x3 (48K) | B x2 (32K)
  char* pA0 = smem;
  char* pA1 = smem + 16384;
  char* pA2 = smem + 32768;
  char* B0  = smem + 49152;
  char* B1  = smem + 65536;

  int tid = threadIdx.x;
  int lane = tid & 63;
  int w = tid >> 6;
  int wr = (w >> 1) * 64, wc = (w & 1) * 32;
  int ln15 = lane & 15, g4 = lane >> 4;

  // A staging (gld16, linear LDS dest + inverse-swizzled source); gather via rtok
  const u16* aptr[4]; int soff[4];
  #pragma unroll
  for (int it = 0; it < 4; ++it) {
    int row = it * 32 + (tid >> 3);
    int p = m0 + row;
    int pp = (p < cntE) ? p : (cntE - 1);
    int tok = rtok[base + pp];
    int c16 = (tid & 7) ^ (row & 7);
    soff[it] = it * 4096 + tid * 16;
    aptr[it] = xb + (size_t)tok * H_DIM + c16 * 8;
  }

  // B staging: thread = (col-group cg: 4 cols, k-group kg: 8 ks)
  int cg = tid & 31, kg = tid >> 5;
  const float* bsrc = (cg < 16)
      ? (wg + (size_t)e * H_DIM * I_DIM + n0 + cg * 4)
      : (wu + (size_t)e * H_DIM * I_DIM + n0 + (cg - 16) * 4);
  int bwb[4];
  #pragma unroll
  for (int ii = 0; ii < 4; ++ii) {
    int row = cg * 4 + ii;
    bwb[ii] = row * 128 + ((kg ^ ((row ^ (row >> 2)) & 7)) << 4);
  }

  // fragment read offsets
  int aoff[4];
  #pragma unroll
  for (int m = 0; m < 4; ++m) aoff[m] = (wr + m * 16 + ln15) * 128;
  int bro[4], bsz[4];
  #pragma unroll
  for (int n = 0; n < 4; ++n) {
    int brow = (n < 2) ? (wc + n * 16 + ln15) : (64 + wc + (n - 2) * 16 + ln15);
    bro[n] = brow * 128;
    bsz[n] = ((brow ^ (brow >> 2)) & 7) << 4;
  }
  int la7_4 = (lane & 7) << 4;

  f32x4v acc[4][4];
  #pragma unroll
  for (int m = 0; m < 4; ++m)
    #pragma unroll
    for (int n = 0; n < 4; ++n) acc[m][n] = f32x4v{0, 0, 0, 0};

  float4 bv0[8], bv1[8];

#define G1_ISSA(kq, AB) { \
  _Pragma("unroll") for (int it = 0; it < 4; ++it) \
    gld16(aptr[it] + (size_t)(kq) * 64, (AB) + soff[it]); }

#define G1_LOADB(S, kq) { \
  const float* _p = bsrc + (size_t)((kq) * 64 + kg * 8) * I_DIM; \
  bv##S[0] = *(const float4*)(_p); \
  bv##S[1] = *(const float4*)(_p + 1 * I_DIM); \
  bv##S[2] = *(const float4*)(_p + 2 * I_DIM); \
  bv##S[3] = *(const float4*)(_p + 3 * I_DIM); \
  bv##S[4] = *(const float4*)(_p + 4 * I_DIM); \
  bv##S[5] = *(const float4*)(_p + 5 * I_DIM); \
  bv##S[6] = *(const float4*)(_p + 6 * I_DIM); \
  bv##S[7] = *(const float4*)(_p + 7 * I_DIM); }

#define G1_CVTW(S, BUF) { \
  _Pragma("unroll") for (int ii = 0; ii < 4; ++ii) { \
    uint4 _v; \
    _v.x = cvtpk((&bv##S[0].x)[ii], (&bv##S[1].x)[ii]); \
    _v.y = cvtpk((&bv##S[2].x)[ii], (&bv##S[3].x)[ii]); \
    _v.z = cvtpk((&bv##S[4].x)[ii], (&bv##S[5].x)[ii]); \
    _v.w = cvtpk((&bv##S[6].x)[ii], (&bv##S[7].x)[ii]); \
    *(uint4*)((BUF) + bwb[ii]) = _v; } }

#define G1_MFMA(AB, BB) { \
  _Pragma("unroll") for (int kk = 0; kk < 2; ++kk) { \
    int xo = (kk * 4 + g4) << 4; \
    short8v a[4], b[4]; \
    _Pragma("unroll") for (int m = 0; m < 4; ++m) \
      a[m] = *(const short8v*)((AB) + aoff[m] + (xo ^ la7_4)); \
    _Pragma("unroll") for (int n = 0; n < 4; ++n) \
      b[n] = *(const short8v*)((BB) + bro[n] + (xo ^ bsz[n])); \
    _Pragma("unroll") for (int m = 0; m < 4; ++m) \
      _Pragma("unroll") for (int n = 0; n < 4; ++n) \
        acc[m][n] = __builtin_amdgcn_mfma_f32_16x16x32_bf16(a[m], b[n], acc[m][n], 0, 0, 0); \
  } }

  // ---- prologue: A(0),A(1); B(0),B(1) regs; stage B(0) ----
  G1_ISSA(0, pA0);
  G1_ISSA(1, pA1); SB0;
  G1_LOADB(0, 0);
  G1_LOADB(1, 1);
  G1_CVTW(0, B0);
  WAITBAR12;

  char* Ac = pA0; char* An = pA1; char* Af = pA2;
  #pragma unroll 1
  for (int kq = 0; kq + 4 <= NK1; kq += 2) {
    // body kq (even)
    G1_ISSA(kq + 2, Af); SB0;
    G1_LOADB(0, kq + 2);
    G1_MFMA(Ac, B0);
    G1_CVTW(1, B1);
    WAITBAR12;
    ROT3(Ac, An, Af);
    // body kq+1 (odd)
    G1_ISSA(kq + 3, Af); SB0;
    G1_LOADB(1, kq + 3);
    G1_MFMA(Ac, B1);
    G1_CVTW(0, B0);
    WAITBAR12;
    ROT3(Ac, An, Af);
  }
  // body NK1-2 (even): nothing left to issue
  G1_MFMA(Ac, B0);
  G1_CVTW(1, B1);
  WAITBAR0;
  ROT3(Ac, An, Af);
  // body NK1-1 (odd)
  G1_MFMA(Ac, B1);

  // epilogue: silu(g)*u*wt -> bf16
  #pragma unroll
  for (int m = 0; m < 4; ++m) {
    #pragma unroll
    for (int r = 0; r < 4; ++r) {
      int row = wr + m * 16 + g4 * 4 + r;
      if (m0 + row < cntE) {
        float wt = rwt[base + m0 + row];
        size_t orow = (size_t)(base + m0 + row) * I_DIM + n0 + wc;
        #pragma unroll
        for (int j = 0; j < 2; ++j) {
          float g = acc[m][j][r], u = acc[m][j + 2][r];
          float aa = g / (1.f + __expf(-g)) * u * wt;
          abuf[orow + j * 16 + ln15] = f2b(aa);
        }
      }
    }
  }
#undef G1_ISSA
#undef G1_LOADB
#undef G1_CVTW
#undef G1_MFMA
}

// ================= GEMM2: abuf @ w_down -> pbuf (f32 grouped rows) ================
__global__ __launch_bounds__(256, 2) void gemm2_kernel(
    const u16* __restrict__ abuf, const float* __restrict__ wd,
    const int* __restrict__ cnt, const int* __restrict__ offs,
    const int* __restrict__ mbe, const int* __restrict__ mbm0,
    const int* __restrict__ mbn, float* __restrict__ pbuf) {
  int mb = blockIdx.y;
  if (mb >= mbn[0]) return;
  int e = mbe[mb];
  int m0 = mbm0[mb];
  int cntE = cnt[e];
  int n0 = blockIdx.x * 128;
  int base = offs[e];

  __shared__ alignas(16) char smem[81920];
  char* pA0 = smem;
  char* pA1 = smem + 16384;
  char* pA2 = smem + 32768;
  char* B0  = smem + 49152;
  char* B1  = smem + 65536;

  int tid = threadIdx.x;
  int lane = tid & 63;
  int w = tid >> 6;
  int wr = (w >> 1) * 64, wc = (w & 1) * 64;
  int ln15 = lane & 15, g4 = lane >> 4;

  const u16* aptr[4]; int soff[4];
  #pragma unroll
  for (int it = 0; it < 4; ++it) {
    int row = it * 32 + (tid >> 3);
    int p = m0 + row;
    int pp = (p < cntE) ? p : (cntE - 1);
    int c16 = (tid & 7) ^ (row & 7);
    soff[it] = it * 4096 + tid * 16;
    aptr[it] = abuf + (size_t)(base + pp) * I_DIM + c16 * 8;
  }

  int cg = tid & 31, kg = tid >> 5;
  const float* bsrc = wd + (size_t)e * I_DIM * H_DIM + n0 + cg * 4;
  int bwb[4];
  #pragma unroll
  for (int ii = 0; ii < 4; ++ii) {
    int row = cg * 4 + ii;
    bwb[ii] = row * 128 + ((kg ^ ((row ^ (row >> 2)) & 7)) << 4);
  }

  int aoff[4];
  #pragma unroll
  for (int m = 0; m < 4; ++m) aoff[m] = (wr + m * 16 + ln15) * 128;
  int bro[4], bsz[4];
  #pragma unroll
  for (int n = 0; n < 4; ++n) {
    int brow = wc + n * 16 + ln15;
    bro[n] = brow * 128;
    bsz[n] = ((brow ^ (brow >> 2)) & 7) << 4;
  }
  int la7_4 = (lane & 7) << 4;

  f32x4v acc[4][4];
  #pragma unroll
  for (int m = 0; m < 4; ++m)
    #pragma unroll
    for (int n = 0; n < 4; ++n) acc[m][n] = f32x4v{0, 0, 0, 0};

  float4 bv0[8], bv1[8];

#define G2_ISSA(kq, AB) { \
  _Pragma("unroll") for (int it = 0; it < 4; ++it) \
    gld16(aptr[it] + (size_t)(kq) * 64, (AB) + soff[it]); }

#define G2_LOADB(S, kq) { \
  const float* _p = bsrc + (size_t)((kq) * 64 + kg * 8) * H_DIM; \
  bv##S[0] = *(const float4*)(_p); \
  bv##S[1] = *(const float4*)(_p + 1 * H_DIM); \
  bv##S[2] = *(const float4*)(_p + 2 * H_DIM); \
  bv##S[3] = *(const float4*)(_p + 3 * H_DIM); \
  bv##S[4] = *(const float4*)(_p + 4 * H_DIM); \
  bv##S[5] = *(const float4*)(_p + 5 * H_DIM); \
  bv##S[6] = *(const float4*)(_p + 6 * H_DIM); \
  bv##S[7] = *(const float4*)(_p + 7 * H_DIM); }

#define G2_CVTW(S, BUF) { \
  _Pragma("unroll") for (int ii = 0; ii < 4; ++ii) { \
    uint4 _v; \
    _v.x = cvtpk((&bv##S[0].x)[ii], (&bv##S[1].x)[ii]); \
    _v.y = cvtpk((&bv##S[2].x)[ii], (&bv##S[3].x)[ii]); \
    _v.z = cvtpk((&bv##S[4].x)[ii], (&bv##S[5].x)[ii]); \
    _v.w = cvtpk((&bv##S[6].x)[ii], (&bv##S[7].x)[ii]); \
    *(uint4*)((BUF) + bwb[ii]) = _v; } }

#define G2_MFMA(AB, BB) { \
  _Pragma("unroll") for (int kk = 0; kk < 2; ++kk) { \
    int xo = (kk * 4 + g4) << 4; \
    short8v a[4], b[4]; \
    _Pragma("unroll") for (int m = 0; m < 4; ++m) \
      a[m] = *(const short8v*)((AB) + aoff[m] + (xo ^ la7_4)); \
    _Pragma("unroll") for (int n = 0; n < 4; ++n) \
      b[n] = *(const short8v*)((BB) + bro[n] + (xo ^ bsz[n])); \
    _Pragma("unroll") for (int m = 0; m < 4; ++m) \
      _Pragma("unroll") for (int n = 0; n < 4; ++n) \
        acc[m][n] = __builtin_amdgcn_mfma_f32_16x16x32_bf16(a[m], b[n], acc[m][n], 0, 0, 0); \
  } }

  G2_ISSA(0, pA0);
  G2_ISSA(1, pA1); SB0;
  G2_LOADB(0, 0);
  G2_LOADB(1, 1);
  G2_CVTW(0, B0);
  WAITBAR12;

  char* Ac = pA0; char* An = pA1; char* Af = pA2;
  #pragma unroll 1
  for (int kq = 0; kq + 4 <= NK2; kq += 2) {
    G2_ISSA(kq + 2, Af); SB0;
    G2_LOADB(0, kq + 2);
    G2_MFMA(Ac, B0);
    G2_CVTW(1, B1);
    WAITBAR12;
    ROT3(Ac, An, Af);
    G2_ISSA(kq + 3, Af); SB0;
    G2_LOADB(1, kq + 3);
    G2_MFMA(Ac, B1);
    G2_CVTW(0, B0);
    WAITBAR12;
    ROT3(Ac, An, Af);
  }
  G2_MFMA(Ac, B0);
  G2_CVTW(1, B1);
  WAITBAR0;
  ROT3(Ac, An, Af);
  G2_MFMA(Ac, B1);

  #pragma unroll
  for (int m = 0; m < 4; ++m) {
    #pragma unroll
    for (int r = 0; r < 4; ++r) {
      int row = wr + m * 16 + g4 * 4 + r;
      if (m0 + row < cntE) {
        float* orow = pbuf + (size_t)(base + m0 + row) * H_DIM + n0 + wc;
        #pragma unroll
        for (int n = 0; n < 4; ++n)
          orow[n * 16 + ln15] = acc[m][n][r];
      }
    }
  }
#undef G2_ISSA
#undef G2_LOADB
#undef G2_CVTW
#undef G2_MFMA
}

// ---------- combine: out[t] = sum_k pbuf[ppos[t][k]] ----------
__global__ __launch_bounds__(256) void combine_kernel(const float* __restrict__ pbuf,
                                                      const int* __restrict__ ppos,
                                                      float* __restrict__ out) {
  int idx = blockIdx.x * 256 + threadIdx.x;
  int t = idx >> 9;
  int h4 = (idx & 511) * 4;
  int4 pp = ((const int4*)ppos)[t];
  float4 s0 = *(const float4*)&pbuf[(size_t)pp.x * H_DIM + h4];
  float4 s1 = *(const float4*)&pbuf[(size_t)pp.y * H_DIM + h4];
  float4 s2 = *(const float4*)&pbuf[(size_t)pp.z * H_DIM + h4];
  float4 s3 = *(const float4*)&pbuf[(size_t)pp.w * H_DIM + h4];
  float4 o;
  o.x = s0.x + s1.x + s2.x + s3.x;
  o.y = s0.y + s1.y + s2.y + s3.y;
  o.z = s0.z + s1.z + s2.z + s3.z;
  o.w = s0.w + s1.w + s2.w + s3.w;
  *(float4*)&out[(size_t)t * H_DIM + h4] = o;
}

// ---------- launch ----------
extern "C" void kernel_launch(void* const* d_in, const int* in_sizes, int n_in,
                              void* d_out, int out_size, void* d_ws, size_t ws_size,
                              hipStream_t stream) {
  (void)in_sizes; (void)n_in; (void)out_size;
  if (ws_size < WS_NEED) return;

  const float* x  = (const float*)d_in[0];
  const float* rw = (const float*)d_in[1];
  const float* wg = (const float*)d_in[2];
  const float* wu = (const float*)d_in[3];
  const float* wd = (const float*)d_in[4];
  float* out = (float*)d_out;
  float* logits = out + (size_t)T_TOK * H_DIM;

  char* ws = (char*)d_ws;
  u16* xb    = (u16*)(ws + OFF_XB);
  u16* abuf  = (u16*)(ws + OFF_ABUF);
  float* pbuf = (float*)(ws + OFF_PBUF);
  int* sel   = (int*)(ws + OFF_SEL);
  float* wts = (float*)(ws + OFF_WTS);
  int* cnt   = (int*)(ws + OFF_CNT);
  int* offs  = (int*)(ws + OFF_OFFS);
  int* curs  = (int*)(ws + OFF_CURS);
  int* rtok  = (int*)(ws + OFF_RTOK);
  float* rwt = (float*)(ws + OFF_RWT);
  int* ppos  = (int*)(ws + OFF_PPOS);
  int* mbe   = (int*)(ws + OFF_MBE);
  int* mbm0  = (int*)(ws + OFF_MBM0);
  int* mbn   = (int*)(ws + OFF_MBN);

  hipMemsetAsync(ws + OFF_CNT, 0, 128, stream);

  cvt_x_kernel<<<(T_TOK * H_DIM / 8) / 256, 256, 0, stream>>>(x, xb);
  router_kernel<<<T_TOK / 4, 256, 0, stream>>>(x, rw, logits, sel, wts);
  hist_kernel<<<(T_TOK * TOPK) / 256, 256, 0, stream>>>(sel, cnt);
  prefix_kernel<<<1, 64, 0, stream>>>(cnt, offs, curs, mbe, mbm0, mbn);
  scatter_kernel<<<(T_TOK * TOPK) / 256, 256, 0, stream>>>(sel, wts, curs, rtok, rwt, ppos);
  gemm1_kernel<<<dim3(I_DIM / 64, MBMAX), 256, 0, stream>>>(xb, wg, wu, cnt, offs, rtok, rwt, mbe, mbm0, mbn, abuf);
  gemm2_kernel<<<dim3(H_DIM / 128, MBMAX), 256, 0, stream>>>(abuf, wd, cnt, offs, mbe, mbm0, mbn, pbuf);
  combine_kernel<<<(T_TOK * (H_DIM / 4)) / 256, 256, 0, stream>>>(pbuf, ppos, out);
}

// Round 8
// 326.219 us; speedup vs baseline: 1.0201x; 1.0201x over previous
//
#include <hip/hip_runtime.h>
#include <hip/hip_bf16.h>

#define H_DIM 2048
#define T_TOK 2048
#define E_NUM 16
#define I_DIM 1024
#define TOPK  4
#define NK1   32   // H_DIM/64
#define NK2   16   // I_DIM/64
#define MBMAX 48   // Sum ceil(cnt_e/256) <= 16 + 8192/256 = 48

typedef short short8v __attribute__((ext_vector_type(8)));
typedef float f32x4v __attribute__((ext_vector_type(4)));
typedef unsigned short u16;
typedef unsigned int u32;

// ---------- ws layout (bytes) ----------
constexpr size_t OFF_XB   = 0;                                     // 8 MiB
constexpr size_t OFF_ABUF = OFF_XB   + (size_t)T_TOK*H_DIM*2;      // 16 MiB
constexpr size_t OFF_SEL  = OFF_ABUF + (size_t)T_TOK*TOPK*I_DIM*2;
constexpr size_t OFF_WTS  = OFF_SEL  + (size_t)T_TOK*TOPK*4;
constexpr size_t OFF_CNT  = OFF_WTS  + (size_t)T_TOK*TOPK*4;
constexpr size_t OFF_OFFS = OFF_CNT  + 128;
constexpr size_t OFF_CURS = OFF_OFFS + 128;
constexpr size_t OFF_RTOK = OFF_CURS + 128;
constexpr size_t OFF_RWT  = OFF_RTOK + (size_t)T_TOK*TOPK*4;
constexpr size_t OFF_MBE  = OFF_RWT  + (size_t)T_TOK*TOPK*4;
constexpr size_t OFF_MBM0 = OFF_MBE  + 256;
constexpr size_t OFF_MBN  = OFF_MBM0 + 256;
constexpr size_t WS_NEED  = OFF_MBN  + 128;

// ---------- helpers ----------
__device__ __forceinline__ u16 f2b(float f) {   // fp32 -> bf16 RNE
  u32 u = __builtin_bit_cast(u32, f);
  u32 r = (u + 0x7FFFu + ((u >> 16) & 1u)) >> 16;
  return (u16)r;
}

__device__ __forceinline__ u32 cvtpk(float lo, float hi) {
  u32 r;
  asm("v_cvt_pk_bf16_f32 %0, %1, %2" : "=v"(r) : "v"(lo), "v"(hi));
  return r;
}

__device__ __forceinline__ void gld16(const void* g, void* l) {
  __builtin_amdgcn_global_load_lds(
      (const __attribute__((address_space(1))) u32*)g,
      (__attribute__((address_space(3))) u32*)l, 16, 0, 0);
}

// ---------- fp32 -> bf16 (x) ----------
__global__ __launch_bounds__(256) void cvt_x_kernel(const float* __restrict__ src,
                                                    u16* __restrict__ dst) {
  int i = blockIdx.x * 256 + threadIdx.x;
  const float4* s = (const float4*)src + (size_t)i * 2;
  float4 a = s[0], b = s[1];
  uint4 o;
  o.x = (u32)f2b(a.x) | ((u32)f2b(a.y) << 16);
  o.y = (u32)f2b(a.z) | ((u32)f2b(a.w) << 16);
  o.z = (u32)f2b(b.x) | ((u32)f2b(b.y) << 16);
  o.w = (u32)f2b(b.z) | ((u32)f2b(b.w) << 16);
  ((uint4*)dst)[i] = o;
}

// ---------- router ----------
__global__ __launch_bounds__(256) void router_kernel(const float* __restrict__ x,
                                                     const float* __restrict__ rw,
                                                     float* __restrict__ logits,
                                                     int* __restrict__ sel,
                                                     float* __restrict__ wts) {
  int w = threadIdx.x >> 6, lane = threadIdx.x & 63;
  int t = blockIdx.x * 4 + w;

  const float4* xt = (const float4*)(x + (size_t)t * H_DIM);
  float4 xv[8];
  #pragma unroll
  for (int j = 0; j < 8; ++j) xv[j] = xt[j * 64 + lane];

  const float4* rw4 = (const float4*)rw;
  float le[E_NUM];
  #pragma unroll
  for (int e = 0; e < E_NUM; ++e) {
    float s = 0.f;
    #pragma unroll
    for (int j = 0; j < 8; ++j) {
      float4 wv = rw4[e * (H_DIM / 4) + j * 64 + lane];
      s += xv[j].x * wv.x + xv[j].y * wv.y + xv[j].z * wv.z + xv[j].w * wv.w;
    }
    #pragma unroll
    for (int off = 32; off; off >>= 1) s += __shfl_xor(s, off);
    le[e] = s;
  }

  int taken = 0;
  float tv[TOPK]; int ti[TOPK];
  #pragma unroll
  for (int k = 0; k < TOPK; ++k) {
    float bv = -1e30f; int bi = 0;
    #pragma unroll
    for (int e = 0; e < E_NUM; ++e) {
      bool ok = !(taken & (1 << e));
      if (ok && le[e] > bv) { bv = le[e]; bi = e; }
    }
    taken |= (1 << bi); tv[k] = bv; ti[k] = bi;
  }
  float m = tv[0];
  float ew[TOPK]; float ssum = 0.f;
  #pragma unroll
  for (int k = 0; k < TOPK; ++k) { ew[k] = __expf(tv[k] - m); ssum += ew[k]; }
  if (lane == 0) {
    #pragma unroll
    for (int e = 0; e < E_NUM; ++e) logits[(size_t)t * E_NUM + e] = le[e];
    float inv = 1.f / ssum;
    #pragma unroll
    for (int k = 0; k < TOPK; ++k) {
      sel[t * TOPK + k] = ti[k];
      wts[t * TOPK + k] = ew[k] * inv;
    }
  }
}

// ---------- grouping ----------
__global__ void hist_kernel(const int* __restrict__ sel, int* __restrict__ cnt) {
  int p = blockIdx.x * 256 + threadIdx.x;
  if (p < T_TOK * TOPK) atomicAdd(&cnt[sel[p]], 1);
}

__global__ void prefix_kernel(const int* __restrict__ cnt, int* __restrict__ offs,
                              int* __restrict__ curs, int* __restrict__ mbe,
                              int* __restrict__ mbm0, int* __restrict__ mbn) {
  if (threadIdx.x == 0) {
    int a = 0;
    for (int e = 0; e < E_NUM; ++e) { offs[e] = a; curs[e] = a; a += cnt[e]; }
    offs[E_NUM] = a;
    int nb = 0;
    for (int e = 0; e < E_NUM; ++e)
      for (int m0 = 0; m0 < cnt[e]; m0 += 256) {
        mbe[nb] = e; mbm0[nb] = m0; ++nb;
      }
    mbn[0] = nb;
  }
}

__global__ void scatter_kernel(const int* __restrict__ sel, const float* __restrict__ wts,
                               int* __restrict__ curs, int* __restrict__ rtok,
                               float* __restrict__ rwt) {
  int p = blockIdx.x * 256 + threadIdx.x;
  if (p >= T_TOK * TOPK) return;
  int e = sel[p];
  int pos = atomicAdd(&curs[e], 1);
  rtok[pos] = p >> 2;
  rwt[pos] = wts[p];
}

// ================= GEMM1: x @ [gate ; up] -> silu(g)*u*wt -> abuf (bf16) ==========
// 256M x 64 I-cols (128 LDS B-rows: g/u interleaved by 32), BK=64, 512 thr / 8 waves
// (4M x 2N of 64x64-eff). Simple 2-phase: stage (A gld16 + B fp32->cvtpk->b64) ->
// sync -> 32 MFMA/wave -> sync. Fat bodies amortize per-body latency cost.
__global__ __launch_bounds__(512) void gemm1_kernel(
    const u16* __restrict__ xb, const float* __restrict__ wg, const float* __restrict__ wu,
    const int* __restrict__ cnt, const int* __restrict__ offs,
    const int* __restrict__ rtok, const float* __restrict__ rwt,
    u16* __restrict__ abuf) {
  int mb = blockIdx.y;
  const int* mbn = cnt + 24;  // see launch: mbn passed via cnt+? -- NO, use params
  (void)mbn;
  return; // placeholder removed below
}

// (real gemm1 below; dummy above removed by not launching it)
__global__ __launch_bounds__(512) void gemm1k(
    const u16* __restrict__ xb, const float* __restrict__ wg, const float* __restrict__ wu,
    const int* __restrict__ cnt, const int* __restrict__ offs,
    const int* __restrict__ rtok, const float* __restrict__ rwt,
    const int* __restrict__ mbe, const int* __restrict__ mbm0,
    const int* __restrict__ mbn, u16* __restrict__ abuf) {
  int mb = blockIdx.y;
  if (mb >= mbn[0]) return;
  int e = mbe[mb];
  int m0 = mbm0[mb];
  int cntE = cnt[e];
  int n0 = blockIdx.x * 64;      // 64 I-cols per block
  int base = offs[e];

  __shared__ alignas(16) char As[32768];   // 256 rows x 64k bf16
  __shared__ alignas(16) char Bs[16384];   // 128 rows x 64k bf16

  int tid = threadIdx.x;
  int lane = tid & 63;
  int w = tid >> 6;                 // 0..7
  int wr = (w >> 1) * 64;           // M quadrant
  int wc = w & 1;                   // N half
  int ln15 = lane & 15, g4 = lane >> 4;

  // ---- A staging: 4 x gld16 per thread, gathered rows ----
  const u16* aptr[4]; int soff[4];
  #pragma unroll
  for (int it = 0; it < 4; ++it) {
    int s = it * 512 + tid;
    int row = s >> 3;                       // 0..255
    int p = m0 + row;
    int pp = (p < cntE) ? p : (cntE - 1);
    int tok = rtok[base + pp];
    int c16 = (s & 7) ^ (row & 7);
    soff[it] = s * 16;
    aptr[it] = xb + (size_t)tok * H_DIM + c16 * 8;
  }

  // ---- B staging: thread = (cg: 4 rows, kg: 4 ks) ----
  // LDS rows: [0..31]=gate(n0..+31) [32..63]=up(n0..+31) [64..95]=gate(+32) [96..127]=up(+32)
  int cg = tid & 31, kg = tid >> 5;         // kg 0..15
  int blk = cg >> 3;
  const float* bmat = (blk & 1) ? wu : wg;
  const float* bsrc = bmat + (size_t)e * H_DIM * I_DIM
                      + n0 + (blk >> 1) * 32 + (cg & 7) * 4;
  int bwb[4];
  #pragma unroll
  for (int ii = 0; ii < 4; ++ii) {
    int row = cg * 4 + ii;
    int slot = (kg >> 1) ^ ((row ^ (row >> 2)) & 7);
    bwb[ii] = row * 128 + slot * 16 + (kg & 1) * 8;
  }

  // ---- fragment read offsets ----
  int aoff[4];
  #pragma unroll
  for (int m = 0; m < 4; ++m) aoff[m] = (wr + m * 16 + ln15) * 128;
  int bro[4], bsz[4];
  #pragma unroll
  for (int n = 0; n < 4; ++n) {
    int brow = wc * 64 + ((n < 2) ? (n * 16) : (32 + (n - 2) * 16)) + ln15;
    bro[n] = brow * 128;
    bsz[n] = ((brow ^ (brow >> 2)) & 7) << 4;
  }
  int la7_4 = (lane & 7) << 4;

  f32x4v acc[4][4];
  #pragma unroll
  for (int m = 0; m < 4; ++m)
    #pragma unroll
    for (int n = 0; n < 4; ++n) acc[m][n] = f32x4v{0, 0, 0, 0};

  #pragma unroll 1
  for (int kb = 0; kb < NK1; ++kb) {
    // stage A
    #pragma unroll
    for (int it = 0; it < 4; ++it)
      gld16(aptr[it] + (size_t)kb * 64, As + soff[it]);
    // stage B: 4 float4 loads (k = kb*64 + kg*4 + r), cvt, 4 b64 writes
    {
      const float* p0 = bsrc + (size_t)(kb * 64 + kg * 4) * I_DIM;
      float4 f0 = *(const float4*)(p0);
      float4 f1 = *(const float4*)(p0 + I_DIM);
      float4 f2 = *(const float4*)(p0 + 2 * I_DIM);
      float4 f3 = *(const float4*)(p0 + 3 * I_DIM);
      #pragma unroll
      for (int ii = 0; ii < 4; ++ii) {
        uint2 v;
        v.x = cvtpk((&f0.x)[ii], (&f1.x)[ii]);
        v.y = cvtpk((&f2.x)[ii], (&f3.x)[ii]);
        *(uint2*)(Bs + bwb[ii]) = v;
      }
    }
    __syncthreads();
    #pragma unroll
    for (int kk = 0; kk < 2; ++kk) {
      int xo = (kk * 4 + g4) << 4;
      short8v a[4], b[4];
      #pragma unroll
      for (int m = 0; m < 4; ++m)
        a[m] = *(const short8v*)(As + aoff[m] + (xo ^ la7_4));
      #pragma unroll
      for (int n = 0; n < 4; ++n)
        b[n] = *(const short8v*)(Bs + bro[n] + (xo ^ bsz[n]));
      #pragma unroll
      for (int m = 0; m < 4; ++m)
        #pragma unroll
        for (int n = 0; n < 4; ++n)
          acc[m][n] = __builtin_amdgcn_mfma_f32_16x16x32_bf16(a[m], b[n], acc[m][n], 0, 0, 0);
    }
    __syncthreads();
  }

  // epilogue: silu(g)*u*wt -> bf16; g=acc[m][j], u=acc[m][j+2], col=n0+wc*32+j*16+ln15
  #pragma unroll
  for (int m = 0; m < 4; ++m) {
    #pragma unroll
    for (int r = 0; r < 4; ++r) {
      int row = wr + m * 16 + g4 * 4 + r;
      if (m0 + row < cntE) {
        float wt = rwt[base + m0 + row];
        size_t orow = (size_t)(base + m0 + row) * I_DIM + n0 + wc * 32;
        #pragma unroll
        for (int j = 0; j < 2; ++j) {
          float g = acc[m][j][r], u = acc[m][j + 2][r];
          float aa = g / (1.f + __expf(-g)) * u * wt;
          abuf[orow + j * 16 + ln15] = f2b(aa);
        }
      }
    }
  }
}

// ================= GEMM2: abuf @ w_down -> atomic-add into out (f32) ==============
// 256M x 128 H-cols, BK=64, 512 thr / 8 waves (4M x 2N of 64x64).
__global__ __launch_bounds__(512) void gemm2k(
    const u16* __restrict__ abuf, const float* __restrict__ wd,
    const int* __restrict__ cnt, const int* __restrict__ offs,
    const int* __restrict__ rtok,
    const int* __restrict__ mbe, const int* __restrict__ mbm0,
    const int* __restrict__ mbn, float* __restrict__ out) {
  int mb = blockIdx.y;
  if (mb >= mbn[0]) return;
  int e = mbe[mb];
  int m0 = mbm0[mb];
  int cntE = cnt[e];
  int n0 = blockIdx.x * 128;     // 128 H-cols per block
  int base = offs[e];

  __shared__ alignas(16) char As[32768];
  __shared__ alignas(16) char Bs[16384];

  int tid = threadIdx.x;
  int lane = tid & 63;
  int w = tid >> 6;
  int wr = (w >> 1) * 64;
  int wc = w & 1;
  int ln15 = lane & 15, g4 = lane >> 4;

  const u16* aptr[4]; int soff[4];
  #pragma unroll
  for (int it = 0; it < 4; ++it) {
    int s = it * 512 + tid;
    int row = s >> 3;
    int p = m0 + row;
    int pp = (p < cntE) ? p : (cntE - 1);
    int c16 = (s & 7) ^ (row & 7);
    soff[it] = s * 16;
    aptr[it] = abuf + (size_t)(base + pp) * I_DIM + c16 * 8;
  }

  int cg = tid & 31, kg = tid >> 5;
  const float* bsrc = wd + (size_t)e * I_DIM * H_DIM + n0 + cg * 4;
  int bwb[4];
  #pragma unroll
  for (int ii = 0; ii < 4; ++ii) {
    int row = cg * 4 + ii;
    int slot = (kg >> 1) ^ ((row ^ (row >> 2)) & 7);
    bwb[ii] = row * 128 + slot * 16 + (kg & 1) * 8;
  }

  int aoff[4];
  #pragma unroll
  for (int m = 0; m < 4; ++m) aoff[m] = (wr + m * 16 + ln15) * 128;
  int bro[4], bsz[4];
  #pragma unroll
  for (int n = 0; n < 4; ++n) {
    int brow = wc * 64 + n * 16 + ln15;
    bro[n] = brow * 128;
    bsz[n] = ((brow ^ (brow >> 2)) & 7) << 4;
  }
  int la7_4 = (lane & 7) << 4;

  f32x4v acc[4][4];
  #pragma unroll
  for (int m = 0; m < 4; ++m)
    #pragma unroll
    for (int n = 0; n < 4; ++n) acc[m][n] = f32x4v{0, 0, 0, 0};

  #pragma unroll 1
  for (int kb = 0; kb < NK2; ++kb) {
    #pragma unroll
    for (int it = 0; it < 4; ++it)
      gld16(aptr[it] + (size_t)kb * 64, As + soff[it]);
    {
      const float* p0 = bsrc + (size_t)(kb * 64 + kg * 4) * H_DIM;
      float4 f0 = *(const float4*)(p0);
      float4 f1 = *(const float4*)(p0 + H_DIM);
      float4 f2 = *(const float4*)(p0 + 2 * H_DIM);
      float4 f3 = *(const float4*)(p0 + 3 * H_DIM);
      #pragma unroll
      for (int ii = 0; ii < 4; ++ii) {
        uint2 v;
        v.x = cvtpk((&f0.x)[ii], (&f1.x)[ii]);
        v.y = cvtpk((&f2.x)[ii], (&f3.x)[ii]);
        *(uint2*)(Bs + bwb[ii]) = v;
      }
    }
    __syncthreads();
    #pragma unroll
    for (int kk = 0; kk < 2; ++kk) {
      int xo = (kk * 4 + g4) << 4;
      short8v a[4], b[4];
      #pragma unroll
      for (int m = 0; m < 4; ++m)
        a[m] = *(const short8v*)(As + aoff[m] + (xo ^ la7_4));
      #pragma unroll
      for (int n = 0; n < 4; ++n)
        b[n] = *(const short8v*)(Bs + bro[n] + (xo ^ bsz[n]));
      #pragma unroll
      for (int m = 0; m < 4; ++m)
        #pragma unroll
        for (int n = 0; n < 4; ++n)
          acc[m][n] = __builtin_amdgcn_mfma_f32_16x16x32_bf16(a[m], b[n], acc[m][n], 0, 0, 0);
    }
    __syncthreads();
  }

  #pragma unroll
  for (int m = 0; m < 4; ++m) {
    #pragma unroll
    for (int r = 0; r < 4; ++r) {
      int row = wr + m * 16 + g4 * 4 + r;
      if (m0 + row < cntE) {
        int tok = rtok[base + m0 + row];
        float* orow = out + (size_t)tok * H_DIM + n0 + wc * 64;
        #pragma unroll
        for (int n = 0; n < 4; ++n)
          unsafeAtomicAdd(&orow[n * 16 + ln15], acc[m][n][r]);
      }
    }
  }
}

// ---------- launch ----------
extern "C" void kernel_launch(void* const* d_in, const int* in_sizes, int n_in,
                              void* d_out, int out_size, void* d_ws, size_t ws_size,
                              hipStream_t stream) {
  (void)in_sizes; (void)n_in;
  if (ws_size < WS_NEED) return;

  const float* x  = (const float*)d_in[0];
  const float* rw = (const float*)d_in[1];
  const float* wg = (const float*)d_in[2];
  const float* wu = (const float*)d_in[3];
  const float* wd = (const float*)d_in[4];
  float* out = (float*)d_out;
  float* logits = out + (size_t)T_TOK * H_DIM;

  char* ws = (char*)d_ws;
  u16* xb    = (u16*)(ws + OFF_XB);
  u16* abuf  = (u16*)(ws + OFF_ABUF);
  int* sel   = (int*)(ws + OFF_SEL);
  float* wts = (float*)(ws + OFF_WTS);
  int* cnt   = (int*)(ws + OFF_CNT);
  int* offs  = (int*)(ws + OFF_OFFS);
  int* curs  = (int*)(ws + OFF_CURS);
  int* rtok  = (int*)(ws + OFF_RTOK);
  float* rwt = (float*)(ws + OFF_RWT);
  int* mbe   = (int*)(ws + OFF_MBE);
  int* mbm0  = (int*)(ws + OFF_MBM0);
  int* mbn   = (int*)(ws + OFF_MBN);

  // out accumulated atomically -> must be zeroed every call (harness doesn't re-poison)
  hipMemsetAsync(d_out, 0, (size_t)out_size * sizeof(float), stream);
  hipMemsetAsync(ws + OFF_CNT, 0, 128, stream);

  cvt_x_kernel<<<(T_TOK * H_DIM / 8) / 256, 256, 0, stream>>>(x, xb);
  router_kernel<<<T_TOK / 4, 256, 0, stream>>>(x, rw, logits, sel, wts);
  hist_kernel<<<(T_TOK * TOPK) / 256, 256, 0, stream>>>(sel, cnt);
  prefix_kernel<<<1, 64, 0, stream>>>(cnt, offs, curs, mbe, mbm0, mbn);
  scatter_kernel<<<(T_TOK * TOPK) / 256, 256, 0, stream>>>(sel, wts, curs, rtok, rwt);
  gemm1k<<<dim3(I_DIM / 64, MBMAX), 512, 0, stream>>>(xb, wg, wu, cnt, offs, rtok, rwt, mbe, mbm0, mbn, abuf);
  gemm2k<<<dim3(H_DIM / 128, MBMAX), 512, 0, stream>>>(abuf, wd, cnt, offs, rtok, mbe, mbm0, mbn, out);
}